// Round 3
// baseline (1071.217 us; speedup 1.0000x reference)
//
#include <hip/hip_runtime.h>

typedef unsigned int uint;
typedef unsigned short ushort;
typedef __attribute__((ext_vector_type(8))) short bf16x8;
typedef __attribute__((ext_vector_type(4))) float f32x4;

#define HWSZ 65536
#define CIN 192
#define C3 576
#define CQK 384

typedef __attribute__((address_space(1))) const void gvoid_c;
typedef __attribute__((address_space(3))) void lvoid;

__device__ __forceinline__ void async16(void* l, const void* g) {
  __builtin_amdgcn_global_load_lds((gvoid_c*)g, (lvoid*)l, 16, 0, 0);
}

__device__ __forceinline__ ushort f2bf(float f) {
  uint u = __float_as_uint(f);
  return (ushort)((u + 0x7fffu + ((u >> 16) & 1u)) >> 16);
}
__device__ __forceinline__ float bflo(uint u) { return __uint_as_float(u << 16); }
__device__ __forceinline__ float bfhi(uint u) { return __uint_as_float(u & 0xffff0000u); }

// ---------------- K0a: x fp32 [b][c][n] -> bf16 [b][n][c], LDS-staged ----------------
__global__ __launch_bounds__(256) void k0_transpose(const float* __restrict__ x,
                                                    ushort* __restrict__ xT) {
  __shared__ ushort lds_t[192 * 66];
  int id = blockIdx.x;
  int n0 = (id & 1023) << 6;
  int b = id >> 10;
  int tid = threadIdx.x;
  int nl = tid & 63;
  int cq = tid >> 6;
  const float* xb = x + (long)b * CIN * HWSZ + n0;
#pragma unroll 4
  for (int j = 0; j < 48; ++j) {
    int c = cq + 4 * j;
    lds_t[c * 66 + nl] = f2bf(xb[(long)c * HWSZ + nl]);
  }
  __syncthreads();
  ushort* ob = xT + (long)b * HWSZ * CIN + (long)n0 * CIN;
  int l = tid & 63, w = tid >> 6;
#pragma unroll
  for (int jj = 0; jj < 6; ++jj) {
    int n = w * 16 + (l & 15);
    int m = jj * 4 + (l >> 4);
    int cb = m * 8;
    ushort v[8];
#pragma unroll
    for (int k = 0; k < 8; ++k) v[k] = lds_t[(cb + k) * 66 + n];
    uint4 pk;
    pk.x = (uint)v[0] | ((uint)v[1] << 16);
    pk.y = (uint)v[2] | ((uint)v[3] << 16);
    pk.z = (uint)v[4] | ((uint)v[5] << 16);
    pk.w = (uint)v[6] | ((uint)v[7] << 16);
    *(uint4*)(ob + (long)n * CIN + cb) = pk;
  }
}

// ---------------- K0b: fp32 -> bf16 flat convert (qkv_w) ----------------
__global__ __launch_bounds__(256) void k0_cvtw(const float* __restrict__ w,
                                               ushort* __restrict__ wb, int nelem) {
  int i = (blockIdx.x * 256 + threadIdx.x) * 4;
  if (i + 3 < nelem) {
    float4 f = *(const float4*)(w + i);
    ushort4 o;
    o.x = f2bf(f.x); o.y = f2bf(f.y); o.z = f2bf(f.z); o.w = f2bf(f.w);
    *(ushort4*)(wb + i) = o;
  }
}

// ---------------- GEMM NT v2: D[M,HW] = A[M,192] * B[HW,192]^T, BN=128 -------------
// BM=192, BN=128, 3 kits of K=64. LDS 46 KB -> 3 blocks/CU (24 waves).
// mtile-fastest block order: 3 siblings sharing a B-tile dispatch consecutively.
template <typename TOut>
__global__ __launch_bounds__(512, 6) void gemm_nt(const ushort* __restrict__ A, long a_bstride,
                                                  const ushort* __restrict__ B, long b_bstride,
                                                  TOut* __restrict__ D, long d_bstride,
                                                  int mtiles) {
  __shared__ ushort lds[23040];  // A: 192*144B = 27648B, B: 128*144B = 18432B
  int idx = blockIdx.x;
  int mtile = idx % 3;           // mtile fastest (B-tile reuse locality)
  int t = idx / 3;
  int ntile = t & 511;
  int b = t >> 9;
  int tid = threadIdx.x;
  int lane = tid & 63;
  int wv = tid >> 6;
  int wm = wv >> 1, wn = wv & 1;  // 4 M-waves x 2 N-waves
  int lanelo = lane & 15, laneq = lane >> 4;

  const ushort* Ab = A + a_bstride * b + (long)mtile * 192 * 192;
  const ushort* Bb = B + b_bstride * b + (long)ntile * 128 * 192;

  f32x4 acc[3][4] = {};

  for (int kit = 0; kit < 3; ++kit) {
#pragma unroll
    for (int i = 0; i < 6; ++i) {
      int wbase = i * 512 + wv * 64;
      if (wbase < 2880) {
        int c = wbase + lane;
        bool isA = c < 1728;
        int local = isA ? c : c - 1728;
        int row = local / 9;
        int sub = local % 9;
        if (sub < 8) {
          const ushort* g = (isA ? Ab : Bb) + row * 192 + kit * 64 + sub * 8;
          async16((char*)lds + wbase * 16, g);
        }
      }
    }
    __syncthreads();
#pragma unroll
    for (int ks = 0; ks < 2; ++ks) {
      bf16x8 af[3], bf[4];
#pragma unroll
      for (int mt = 0; mt < 3; ++mt) {
        int m = wm * 48 + mt * 16 + lanelo;
        af[mt] = *(const bf16x8*)((const char*)lds + m * 144 + ks * 64 + laneq * 16);
      }
#pragma unroll
      for (int nt = 0; nt < 4; ++nt) {
        int n = wn * 64 + nt * 16 + lanelo;
        bf[nt] = *(const bf16x8*)((const char*)lds + 27648 + n * 144 + ks * 64 + laneq * 16);
      }
#pragma unroll
      for (int mt = 0; mt < 3; ++mt)
#pragma unroll
        for (int nt = 0; nt < 4; ++nt)
          acc[mt][nt] = __builtin_amdgcn_mfma_f32_16x16x32_bf16(af[mt], bf[nt], acc[mt][nt], 0, 0, 0);
    }
    __syncthreads();
  }

  TOut* Db = D + d_bstride * b;
  int colb = ntile * 128 + wn * 64 + lanelo;
#pragma unroll
  for (int mt = 0; mt < 3; ++mt)
#pragma unroll
    for (int nt = 0; nt < 4; ++nt)
#pragma unroll
      for (int r = 0; r < 4; ++r) {
        long row = (long)(mtile * 192 + wm * 48 + mt * 16 + laneq * 4 + r);
        float v = acc[mt][nt][r];
        if constexpr (sizeof(TOut) == 2)
          Db[row * HWSZ + colb + nt * 16] = f2bf(v);
        else
          Db[row * HWSZ + colb + nt * 16] = v;
      }
}

// ---------------- GEMM NN: D[M,HW] = A[M,192] * B[192,HW] (B in [c][n]) ------------
// B-tile reg-staged coalesced from [c][n], written transposed into the same [n][c]
// LDS layout the MFMA path consumes. XOR block-swizzle keeps ds_write_b16 2-way.
template <typename TOut>
__global__ __launch_bounds__(512, 4) void gemm_nn(const ushort* __restrict__ A, long a_bstride,
                                                  const ushort* __restrict__ B, long b_bstride,
                                                  TOut* __restrict__ D, long d_bstride,
                                                  int mtiles) {
  __shared__ ushort lds[18432];  // A: 27648B, B(transposed): 64*144B = 9216B
  int idx = blockIdx.x;
  int ntile = idx & 1023;
  int bm = idx >> 10;
  int mtile = bm % mtiles;
  int b = bm / mtiles;
  int tid = threadIdx.x;
  int lane = tid & 63;
  int wv = tid >> 6;
  int wm = wv >> 1, wn = wv & 1;
  int lanelo = lane & 15, laneq = lane >> 4;

  const ushort* Ab = A + a_bstride * b + (long)mtile * 192 * 192;
  const ushort* Bb = B + b_bstride * b + (long)ntile * 64;  // [c][n] layout, row stride HWSZ

  int cs = tid >> 3, chk = tid & 7;     // cs: 0..63 c-slice row, chk: n-octet
  ushort* lb = lds + 13824;             // B region, ushort units (27648 B)

  f32x4 acc[3][2] = {};

  for (int kit = 0; kit < 3; ++kit) {
    // B: coalesced reg load (8 x 128B segments per wave)
    uint4 bv = *(const uint4*)(Bb + (long)(kit * 64 + cs) * HWSZ + chk * 8);
    // A: async16 direct-to-LDS, 192 rows x 8 subs
#pragma unroll
    for (int i = 0; i < 4; ++i) {
      int wbase = i * 512 + wv * 64;
      if (wbase < 1728) {
        int cc = wbase + lane;
        int row = cc / 9, sub = cc % 9;
        if (sub < 8) {
          const ushort* g = Ab + row * 192 + kit * 64 + sub * 8;
          async16((char*)lds + wbase * 16, g);
        }
      }
    }
    // B: transposed write, col-block swizzled by (n>>3)&7 (== chk here)
    union { uint4 q; ushort u[8]; } pk;
    pk.q = bv;
    int colbase = (((cs >> 3) ^ chk) << 3) | (cs & 7);
#pragma unroll
    for (int j = 0; j < 8; ++j)
      lb[(chk * 8 + j) * 72 + colbase] = pk.u[j];
    __syncthreads();
#pragma unroll
    for (int ks = 0; ks < 2; ++ks) {
      bf16x8 af[3], bf[2];
#pragma unroll
      for (int mt = 0; mt < 3; ++mt) {
        int m = wm * 48 + mt * 16 + lanelo;
        af[mt] = *(const bf16x8*)((const char*)lds + m * 144 + ks * 64 + laneq * 16);
      }
#pragma unroll
      for (int nt = 0; nt < 2; ++nt) {
        int n = wn * 32 + nt * 16 + lanelo;
        int cb = ks * 4 + laneq;
        bf[nt] = *(const bf16x8*)((const char*)lds + 27648 + n * 144 +
                                  ((cb ^ ((n >> 3) & 7)) << 4));
      }
#pragma unroll
      for (int mt = 0; mt < 3; ++mt)
#pragma unroll
        for (int nt = 0; nt < 2; ++nt)
          acc[mt][nt] = __builtin_amdgcn_mfma_f32_16x16x32_bf16(af[mt], bf[nt], acc[mt][nt], 0, 0, 0);
    }
    __syncthreads();
  }

  TOut* Db = D + d_bstride * b;
  int colb = ntile * 64 + wn * 32 + lanelo;
#pragma unroll
  for (int mt = 0; mt < 3; ++mt)
#pragma unroll
    for (int nt = 0; nt < 2; ++nt)
#pragma unroll
      for (int r = 0; r < 4; ++r) {
        long row = (long)(mtile * 192 + wm * 48 + mt * 16 + laneq * 4 + r);
        float v = acc[mt][nt][r];
        if constexpr (sizeof(TOut) == 2)
          Db[row * HWSZ + colb + nt * 16] = f2bf(v);
        else
          Db[row * HWSZ + colb + nt * 16] = v;
      }
}

// ---------------- K2a v2: depthwise 3x3 on q,k channels + sq-norm partials ----------
__global__ __launch_bounds__(256) void k2_qk(const ushort* __restrict__ qkv,
                                             ushort* __restrict__ qkdw,
                                             float* __restrict__ sqp,
                                             const float* __restrict__ dww) {
  __shared__ uint row_lds[34 * 132];  // 17952 B
  __shared__ float red[4];
  int id = blockIdx.x;
  int yt = id & 7;
  int bc = id >> 3;
  int c = bc % CQK;
  int b = bc / CQK;
  int y0 = yt * 32;
  int tid = threadIdx.x;
  const uint* src = (const uint*)qkv + ((long)(b * C3 + c) * HWSZ >> 1);
  for (int i = tid; i < 4488; i += 256) {
    int r = i / 132, wx = i % 132;
    int gy = y0 - 1 + r;
    uint v = 0;
    if (gy >= 0 && gy < 256 && wx >= 1 && wx <= 128) v = src[gy * 128 + wx - 1];
    row_lds[i] = v;
  }
  float w9[9];
#pragma unroll
  for (int j = 0; j < 9; ++j) w9[j] = dww[c * 9 + j];
  __syncthreads();
  int row = tid >> 3;        // 0..31
  int xp0 = (tid & 7) * 16;  // u32 col base
  float ss = 0.f;
  uint* dst = (uint*)qkdw + ((long)(b * CQK + c) * HWSZ >> 1) + (y0 + row) * 128 + xp0;
#pragma unroll
  for (int ch = 0; ch < 4; ++ch) {
    float o0[4] = {0.f, 0.f, 0.f, 0.f}, o1[4] = {0.f, 0.f, 0.f, 0.f};
#pragma unroll
    for (int dy = 0; dy < 3; ++dy) {
      const uint* L = &row_lds[(row + dy) * 132 + xp0 + ch * 4];
      uint4 q4 = *(const uint4*)L;
      uint2 q2 = *(const uint2*)(L + 4);
      uint u[6] = {q4.x, q4.y, q4.z, q4.w, q2.x, q2.y};
      float wa = w9[dy * 3 + 0], wb_ = w9[dy * 3 + 1], wc = w9[dy * 3 + 2];
#pragma unroll
      for (int j = 0; j < 4; ++j) {
        float f0 = bfhi(u[j]), f1 = bflo(u[j + 1]), f2 = bfhi(u[j + 1]), f3 = bflo(u[j + 2]);
        o0[j] += wa * f0 + wb_ * f1 + wc * f2;
        o1[j] += wa * f1 + wb_ * f2 + wc * f3;
      }
    }
    uint4 pk;
    pk.x = (uint)f2bf(o0[0]) | ((uint)f2bf(o1[0]) << 16);
    pk.y = (uint)f2bf(o0[1]) | ((uint)f2bf(o1[1]) << 16);
    pk.z = (uint)f2bf(o0[2]) | ((uint)f2bf(o1[2]) << 16);
    pk.w = (uint)f2bf(o0[3]) | ((uint)f2bf(o1[3]) << 16);
#pragma unroll
    for (int j = 0; j < 4; ++j) ss += o0[j] * o0[j] + o1[j] * o1[j];
    *(uint4*)(dst + ch * 4) = pk;
  }
#pragma unroll
  for (int off = 32; off; off >>= 1) ss += __shfl_down(ss, off);
  if ((tid & 63) == 0) red[tid >> 6] = ss;
  __syncthreads();
  if (tid == 0) sqp[(long)(b * CQK + c) * 8 + yt] = red[0] + red[1] + red[2] + red[3];
}

// ---------------- K2b v3: depthwise 3x3 on v channels, NATURAL [c][n] output --------
__global__ __launch_bounds__(256) void k2_vc(const ushort* __restrict__ qkv,
                                             ushort* __restrict__ vdw,
                                             const float* __restrict__ dww) {
  __shared__ uint row_lds[34 * 132];  // 17952 B
  int id = blockIdx.x;
  int yt = id & 7;
  int bc = id >> 3;
  int c = bc % 192;
  int b = bc / 192;
  int y0 = yt * 32;
  int tid = threadIdx.x;
  const uint* src = (const uint*)qkv + ((long)(b * C3 + CQK + c) * HWSZ >> 1);
  for (int i = tid; i < 4488; i += 256) {
    int r = i / 132, wx = i % 132;
    int gy = y0 - 1 + r;
    uint v = 0;
    if (gy >= 0 && gy < 256 && wx >= 1 && wx <= 128) v = src[gy * 128 + wx - 1];
    row_lds[i] = v;
  }
  float w9[9];
#pragma unroll
  for (int j = 0; j < 9; ++j) w9[j] = dww[(CQK + c) * 9 + j];
  __syncthreads();
  int row = tid >> 3;        // 0..31
  int xp0 = (tid & 7) * 16;  // u32 col base
  uint* dst = (uint*)vdw + ((long)(b * 192 + c) * HWSZ >> 1) + (y0 + row) * 128 + xp0;
#pragma unroll
  for (int ch = 0; ch < 4; ++ch) {
    float o0[4] = {0.f, 0.f, 0.f, 0.f}, o1[4] = {0.f, 0.f, 0.f, 0.f};
#pragma unroll
    for (int dy = 0; dy < 3; ++dy) {
      const uint* L = &row_lds[(row + dy) * 132 + xp0 + ch * 4];
      uint4 q4 = *(const uint4*)L;
      uint2 q2 = *(const uint2*)(L + 4);
      uint u[6] = {q4.x, q4.y, q4.z, q4.w, q2.x, q2.y};
      float wa = w9[dy * 3 + 0], wb_ = w9[dy * 3 + 1], wc = w9[dy * 3 + 2];
#pragma unroll
      for (int j = 0; j < 4; ++j) {
        float f0 = bfhi(u[j]), f1 = bflo(u[j + 1]), f2 = bfhi(u[j + 1]), f3 = bflo(u[j + 2]);
        o0[j] += wa * f0 + wb_ * f1 + wc * f2;
        o1[j] += wa * f1 + wb_ * f2 + wc * f3;
      }
    }
    uint4 pk;
    pk.x = (uint)f2bf(o0[0]) | ((uint)f2bf(o1[0]) << 16);
    pk.y = (uint)f2bf(o0[1]) | ((uint)f2bf(o1[1]) << 16);
    pk.z = (uint)f2bf(o0[2]) | ((uint)f2bf(o1[2]) << 16);
    pk.w = (uint)f2bf(o0[3]) | ((uint)f2bf(o1[3]) << 16);
    *(uint4*)(dst + ch * 4) = pk;
  }
}

// ---------------- K3a v2: attention logit partials (32 chunks, plain stores) --------
__global__ __launch_bounds__(256, 4) void k3_attn(const ushort* __restrict__ qkdw,
                                                  float* __restrict__ rawp) {
  __shared__ ushort qk_lds[96 * 136];  // rows padded to 272B
  int id = blockIdx.x;
  int chunk = id & 31;
  int bh = id >> 5;
  int b = bh >> 2, h = bh & 3;
  int tid = threadIdx.x;
  int lane = tid & 63, wv = tid >> 6;
  int lanelo = lane & 15, laneq = lane >> 4;
  f32x4 acc[3][3] = {};
  long kbase0 = (long)chunk * 2048;
  for (int it = 0; it < 16; ++it) {
    long kb = kbase0 + it * 128;
#pragma unroll
    for (int i = 0; i < 7; ++i) {
      int wbase = i * 256 + wv * 64;
      if (wbase < 1632) {
        int cc = wbase + lane;
        if (cc < 1632) {
          int row = cc / 17, sub = cc % 17;
          if (sub < 16) {
            int chn = (row < 48) ? (h * 48 + row) : (192 + h * 48 + row - 48);
            const ushort* g = qkdw + (long)(b * CQK + chn) * HWSZ + kb + sub * 8;
            async16((char*)qk_lds + wbase * 16, g);
          }
        }
      }
    }
    __syncthreads();
    bf16x8 af[3], bf[3];
#pragma unroll
    for (int mt = 0; mt < 3; ++mt)
      af[mt] = *(const bf16x8*)((const char*)qk_lds + (mt * 16 + lanelo) * 272 + wv * 64 + laneq * 16);
#pragma unroll
    for (int et = 0; et < 3; ++et)
      bf[et] = *(const bf16x8*)((const char*)qk_lds + (48 + et * 16 + lanelo) * 272 + wv * 64 + laneq * 16);
#pragma unroll
    for (int mt = 0; mt < 3; ++mt)
#pragma unroll
      for (int et = 0; et < 3; ++et)
        acc[mt][et] = __builtin_amdgcn_mfma_f32_16x16x32_bf16(af[mt], bf[et], acc[mt][et], 0, 0, 0);
    __syncthreads();
  }
  float* rb = rawp + ((long)bh * 32 + chunk) * 2304;
#pragma unroll
  for (int mt = 0; mt < 3; ++mt)
#pragma unroll
    for (int et = 0; et < 3; ++et)
#pragma unroll
      for (int r = 0; r < 4; ++r) {
        int d = mt * 16 + laneq * 4 + r;
        int e = et * 16 + lanelo;
        rb[d * 48 + e] = acc[mt][et][r];
      }
}

// ---------------- K3b v2: reduce partials + normalize + softmax + fold proj_w -------
__global__ __launch_bounds__(256) void k3_soft(const float* __restrict__ rawp,
                                               const float* __restrict__ sqp,
                                               const float* __restrict__ temp,
                                               const float* __restrict__ projw,
                                               ushort* __restrict__ M) {
  __shared__ float attn[48 * 48];
  __shared__ float iq[48], ik[48];
  int bh = blockIdx.x;
  int b = bh >> 2, h = bh & 3;
  int tid = threadIdx.x;
  if (tid < 48) {
    const float* p = sqp + (long)(b * CQK + h * 48 + tid) * 8;
    float s = 0.f;
#pragma unroll
    for (int k = 0; k < 8; ++k) s += p[k];
    iq[tid] = 1.f / fmaxf(sqrtf(s), 1e-12f);
  } else if (tid < 96) {
    int e = tid - 48;
    const float* p = sqp + (long)(b * CQK + 192 + h * 48 + e) * 8;
    float s = 0.f;
#pragma unroll
    for (int k = 0; k < 8; ++k) s += p[k];
    ik[e] = 1.f / fmaxf(sqrtf(s), 1e-12f);
  }
  __syncthreads();
  float t = temp[h];
  for (int i = tid; i < 2304; i += 256) {
    float s = 0.f;
    const float* rp = rawp + (long)bh * 32 * 2304 + i;
#pragma unroll 8
    for (int ch = 0; ch < 32; ++ch) s += rp[ch * 2304];
    int d = i / 48, e = i % 48;
    attn[i] = s * iq[d] * ik[e] * t;
  }
  __syncthreads();
  if (tid < 48) {
    float mx = -1e30f;
    for (int e = 0; e < 48; ++e) mx = fmaxf(mx, attn[tid * 48 + e]);
    float s = 0.f;
    for (int e = 0; e < 48; ++e) {
      float v = expf(attn[tid * 48 + e] - mx);
      attn[tid * 48 + e] = v;
      s += v;
    }
    float inv = 1.f / s;
    for (int e = 0; e < 48; ++e) attn[tid * 48 + e] *= inv;
  }
  __syncthreads();
  ushort* Mb = M + (long)b * 192 * 192;
  for (int i = tid; i < 192 * 48; i += 256) {
    int cp = i / 48, e = i % 48;
    const float* pw = projw + (long)cp * 192 + h * 48;
    float s = 0.f;
#pragma unroll 4
    for (int d = 0; d < 48; ++d) s += pw[d] * attn[d * 48 + e];
    Mb[(long)cp * 192 + h * 48 + e] = f2bf(s);
  }
}

extern "C" void kernel_launch(void* const* d_in, const int* in_sizes, int n_in,
                              void* d_out, int out_size, void* d_ws, size_t ws_size,
                              hipStream_t stream) {
  const float* x = (const float*)d_in[0];
  const float* qkv_w = (const float*)d_in[1];
  const float* dw_w = (const float*)d_in[2];
  const float* temp = (const float*)d_in[3];
  const float* proj_w = (const float*)d_in[4];

  char* ws = (char*)d_ws;
  ushort* xT = (ushort*)(ws);                      // 100,663,296 B ; reused as vdw [c][n]
  ushort* QKV = (ushort*)(ws + 100663296L);        // 301,989,888 B
  ushort* qkdw = (ushort*)(ws + 402653184L);       // 201,326,592 B
  ushort* wbf = (ushort*)(ws + 603979776L);        // 221,184 B
  ushort* Mbf = (ushort*)(ws + 604200960L);        // 294,912 B
  float* sqp = (float*)(ws + 604495872L);          // 49,152 B
  float* rawp = (float*)(ws + 604545024L);         // 4,718,592 B

  k0_transpose<<<4096, 256, 0, stream>>>(x, xT);
  k0_cvtw<<<108, 256, 0, stream>>>(qkv_w, wbf, 110592);
  gemm_nt<ushort><<<6144, 512, 0, stream>>>(wbf, 0L, xT, (long)HWSZ * CIN, QKV, (long)C3 * HWSZ, 3);
  k2_qk<<<12288, 256, 0, stream>>>(QKV, qkdw, sqp, dw_w);
  k2_vc<<<6144, 256, 0, stream>>>(QKV, xT, dw_w);  // vdw [c][n] overwrites xT (gemm done)
  k3_attn<<<512, 256, 0, stream>>>(qkdw, rawp);
  k3_soft<<<16, 256, 0, stream>>>(rawp, sqp, temp, proj_w, Mbf);
  gemm_nn<float><<<4096, 512, 0, stream>>>(Mbf, (long)192 * 192, xT, (long)192 * HWSZ,
                                           (float*)d_out, (long)CIN * HWSZ, 1);
}

// Round 4
// 1040.358 us; speedup vs baseline: 1.0297x; 1.0297x over previous
//
#include <hip/hip_runtime.h>

typedef unsigned int uint;
typedef unsigned short ushort;
typedef __attribute__((ext_vector_type(8))) short bf16x8;
typedef __attribute__((ext_vector_type(4))) float f32x4;

#define HWSZ 65536
#define CIN 192
#define C3 576
#define CQK 384

typedef __attribute__((address_space(1))) const void gvoid_c;
typedef __attribute__((address_space(3))) void lvoid;

__device__ __forceinline__ void async16(void* l, const void* g) {
  __builtin_amdgcn_global_load_lds((gvoid_c*)g, (lvoid*)l, 16, 0, 0);
}

__device__ __forceinline__ ushort f2bf(float f) {
  uint u = __float_as_uint(f);
  return (ushort)((u + 0x7fffu + ((u >> 16) & 1u)) >> 16);
}
__device__ __forceinline__ float bflo(uint u) { return __uint_as_float(u << 16); }
__device__ __forceinline__ float bfhi(uint u) { return __uint_as_float(u & 0xffff0000u); }

// ---------------- K0a: x fp32 [b][c][n] -> bf16 [b][n][c], LDS-staged ----------------
__global__ __launch_bounds__(256) void k0_transpose(const float* __restrict__ x,
                                                    ushort* __restrict__ xT) {
  __shared__ ushort lds_t[192 * 66];
  int id = blockIdx.x;
  int n0 = (id & 1023) << 6;
  int b = id >> 10;
  int tid = threadIdx.x;
  int nl = tid & 63;
  int cq = tid >> 6;
  const float* xb = x + (long)b * CIN * HWSZ + n0;
#pragma unroll 4
  for (int j = 0; j < 48; ++j) {
    int c = cq + 4 * j;
    lds_t[c * 66 + nl] = f2bf(xb[(long)c * HWSZ + nl]);
  }
  __syncthreads();
  ushort* ob = xT + (long)b * HWSZ * CIN + (long)n0 * CIN;
  int l = tid & 63, w = tid >> 6;
#pragma unroll
  for (int jj = 0; jj < 6; ++jj) {
    int n = w * 16 + (l & 15);
    int m = jj * 4 + (l >> 4);
    int cb = m * 8;
    ushort v[8];
#pragma unroll
    for (int k = 0; k < 8; ++k) v[k] = lds_t[(cb + k) * 66 + n];
    uint4 pk;
    pk.x = (uint)v[0] | ((uint)v[1] << 16);
    pk.y = (uint)v[2] | ((uint)v[3] << 16);
    pk.z = (uint)v[4] | ((uint)v[5] << 16);
    pk.w = (uint)v[6] | ((uint)v[7] << 16);
    *(uint4*)(ob + (long)n * CIN + cb) = pk;
  }
}

// ---------------- K0b: fp32 -> bf16 flat convert (qkv_w) ----------------
__global__ __launch_bounds__(256) void k0_cvtw(const float* __restrict__ w,
                                               ushort* __restrict__ wb, int nelem) {
  int i = (blockIdx.x * 256 + threadIdx.x) * 4;
  if (i + 3 < nelem) {
    float4 f = *(const float4*)(w + i);
    ushort4 o;
    o.x = f2bf(f.x); o.y = f2bf(f.y); o.z = f2bf(f.z); o.w = f2bf(f.w);
    *(ushort4*)(wb + i) = o;
  }
}

// ---------------- GEMM NT v3: D[M,HW] = A[M,192] * B[HW,192]^T, BN=128 -------------
// BM=192, BN=128, 3 kits of K=64. LDS 46 KB -> 3 blocks/CU (24 waves).
// ntile-FASTEST block order (round-2 locality): B passes time-separated per mtile,
// L3 dedupes across passes. mtile-fastest (round-3) tripled HBM fetch — do not reorder.
template <typename TOut>
__global__ __launch_bounds__(512, 6) void gemm_nt(const ushort* __restrict__ A, long a_bstride,
                                                  const ushort* __restrict__ B, long b_bstride,
                                                  TOut* __restrict__ D, long d_bstride,
                                                  int mtiles) {
  __shared__ ushort lds[23040];  // A: 192*144B = 27648B, B: 128*144B = 18432B
  int idx = blockIdx.x;
  int ntile = idx & 511;         // ntile fastest
  int bm = idx >> 9;
  int mtile = bm % mtiles;
  int b = bm / mtiles;
  int tid = threadIdx.x;
  int lane = tid & 63;
  int wv = tid >> 6;
  int wm = wv >> 1, wn = wv & 1;  // 4 M-waves x 2 N-waves
  int lanelo = lane & 15, laneq = lane >> 4;

  const ushort* Ab = A + a_bstride * b + (long)mtile * 192 * 192;
  const ushort* Bb = B + b_bstride * b + (long)ntile * 128 * 192;

  f32x4 acc[3][4] = {};

  for (int kit = 0; kit < 3; ++kit) {
#pragma unroll
    for (int i = 0; i < 6; ++i) {
      int wbase = i * 512 + wv * 64;
      if (wbase < 2880) {
        int c = wbase + lane;
        bool isA = c < 1728;
        int local = isA ? c : c - 1728;
        int row = local / 9;
        int sub = local % 9;
        if (sub < 8) {
          const ushort* g = (isA ? Ab : Bb) + row * 192 + kit * 64 + sub * 8;
          async16((char*)lds + wbase * 16, g);
        }
      }
    }
    __syncthreads();
#pragma unroll
    for (int ks = 0; ks < 2; ++ks) {
      bf16x8 af[3], bf[4];
#pragma unroll
      for (int mt = 0; mt < 3; ++mt) {
        int m = wm * 48 + mt * 16 + lanelo;
        af[mt] = *(const bf16x8*)((const char*)lds + m * 144 + ks * 64 + laneq * 16);
      }
#pragma unroll
      for (int nt = 0; nt < 4; ++nt) {
        int n = wn * 64 + nt * 16 + lanelo;
        bf[nt] = *(const bf16x8*)((const char*)lds + 27648 + n * 144 + ks * 64 + laneq * 16);
      }
#pragma unroll
      for (int mt = 0; mt < 3; ++mt)
#pragma unroll
        for (int nt = 0; nt < 4; ++nt)
          acc[mt][nt] = __builtin_amdgcn_mfma_f32_16x16x32_bf16(af[mt], bf[nt], acc[mt][nt], 0, 0, 0);
    }
    __syncthreads();
  }

  TOut* Db = D + d_bstride * b;
  int colb = ntile * 128 + wn * 64 + lanelo;
#pragma unroll
  for (int mt = 0; mt < 3; ++mt)
#pragma unroll
    for (int nt = 0; nt < 4; ++nt)
#pragma unroll
      for (int r = 0; r < 4; ++r) {
        long row = (long)(mtile * 192 + wm * 48 + mt * 16 + laneq * 4 + r);
        float v = acc[mt][nt][r];
        if constexpr (sizeof(TOut) == 2)
          Db[row * HWSZ + colb + nt * 16] = f2bf(v);
        else
          Db[row * HWSZ + colb + nt * 16] = v;
      }
}

// ---------------- GEMM NN: D[M,HW] = A[M,192] * B[192,HW] (B in [c][n]) ------------
// B-tile reg-staged coalesced from [c][n], written transposed into the same [n][c]
// LDS layout the MFMA path consumes. XOR block-swizzle keeps ds_write_b16 2-way.
template <typename TOut>
__global__ __launch_bounds__(512, 4) void gemm_nn(const ushort* __restrict__ A, long a_bstride,
                                                  const ushort* __restrict__ B, long b_bstride,
                                                  TOut* __restrict__ D, long d_bstride,
                                                  int mtiles) {
  __shared__ ushort lds[18432];  // A: 27648B, B(transposed): 64*144B = 9216B
  int idx = blockIdx.x;
  int ntile = idx & 1023;
  int bm = idx >> 10;
  int mtile = bm % mtiles;
  int b = bm / mtiles;
  int tid = threadIdx.x;
  int lane = tid & 63;
  int wv = tid >> 6;
  int wm = wv >> 1, wn = wv & 1;
  int lanelo = lane & 15, laneq = lane >> 4;

  const ushort* Ab = A + a_bstride * b + (long)mtile * 192 * 192;
  const ushort* Bb = B + b_bstride * b + (long)ntile * 64;  // [c][n] layout, row stride HWSZ

  int cs = tid >> 3, chk = tid & 7;     // cs: 0..63 c-slice row, chk: n-octet
  ushort* lb = lds + 13824;             // B region, ushort units (27648 B)

  f32x4 acc[3][2] = {};

  for (int kit = 0; kit < 3; ++kit) {
    // B: coalesced reg load (8 x 128B segments per wave)
    uint4 bv = *(const uint4*)(Bb + (long)(kit * 64 + cs) * HWSZ + chk * 8);
    // A: async16 direct-to-LDS, 192 rows x 8 subs
#pragma unroll
    for (int i = 0; i < 4; ++i) {
      int wbase = i * 512 + wv * 64;
      if (wbase < 1728) {
        int cc = wbase + lane;
        int row = cc / 9, sub = cc % 9;
        if (sub < 8) {
          const ushort* g = Ab + row * 192 + kit * 64 + sub * 8;
          async16((char*)lds + wbase * 16, g);
        }
      }
    }
    // B: transposed write, col-block swizzled by (n>>3)&7 (== chk here)
    union { uint4 q; ushort u[8]; } pk;
    pk.q = bv;
    int colbase = (((cs >> 3) ^ chk) << 3) | (cs & 7);
#pragma unroll
    for (int j = 0; j < 8; ++j)
      lb[(chk * 8 + j) * 72 + colbase] = pk.u[j];
    __syncthreads();
#pragma unroll
    for (int ks = 0; ks < 2; ++ks) {
      bf16x8 af[3], bf[2];
#pragma unroll
      for (int mt = 0; mt < 3; ++mt) {
        int m = wm * 48 + mt * 16 + lanelo;
        af[mt] = *(const bf16x8*)((const char*)lds + m * 144 + ks * 64 + laneq * 16);
      }
#pragma unroll
      for (int nt = 0; nt < 2; ++nt) {
        int n = wn * 32 + nt * 16 + lanelo;
        int cb = ks * 4 + laneq;
        bf[nt] = *(const bf16x8*)((const char*)lds + 27648 + n * 144 +
                                  ((cb ^ ((n >> 3) & 7)) << 4));
      }
#pragma unroll
      for (int mt = 0; mt < 3; ++mt)
#pragma unroll
        for (int nt = 0; nt < 2; ++nt)
          acc[mt][nt] = __builtin_amdgcn_mfma_f32_16x16x32_bf16(af[mt], bf[nt], acc[mt][nt], 0, 0, 0);
    }
    __syncthreads();
  }

  TOut* Db = D + d_bstride * b;
  int colb = ntile * 64 + wn * 32 + lanelo;
#pragma unroll
  for (int mt = 0; mt < 3; ++mt)
#pragma unroll
    for (int nt = 0; nt < 2; ++nt)
#pragma unroll
      for (int r = 0; r < 4; ++r) {
        long row = (long)(mtile * 192 + wm * 48 + mt * 16 + laneq * 4 + r);
        float v = acc[mt][nt][r];
        if constexpr (sizeof(TOut) == 2)
          Db[row * HWSZ + colb + nt * 16] = f2bf(v);
        else
          Db[row * HWSZ + colb + nt * 16] = v;
      }
}

// ---------------- K2a v2: depthwise 3x3 on q,k channels + sq-norm partials ----------
__global__ __launch_bounds__(256) void k2_qk(const ushort* __restrict__ qkv,
                                             ushort* __restrict__ qkdw,
                                             float* __restrict__ sqp,
                                             const float* __restrict__ dww) {
  __shared__ uint row_lds[34 * 132];  // 17952 B
  __shared__ float red[4];
  int id = blockIdx.x;
  int yt = id & 7;
  int bc = id >> 3;
  int c = bc % CQK;
  int b = bc / CQK;
  int y0 = yt * 32;
  int tid = threadIdx.x;
  const uint* src = (const uint*)qkv + ((long)(b * C3 + c) * HWSZ >> 1);
  for (int i = tid; i < 4488; i += 256) {
    int r = i / 132, wx = i % 132;
    int gy = y0 - 1 + r;
    uint v = 0;
    if (gy >= 0 && gy < 256 && wx >= 1 && wx <= 128) v = src[gy * 128 + wx - 1];
    row_lds[i] = v;
  }
  float w9[9];
#pragma unroll
  for (int j = 0; j < 9; ++j) w9[j] = dww[c * 9 + j];
  __syncthreads();
  int row = tid >> 3;        // 0..31
  int xp0 = (tid & 7) * 16;  // u32 col base
  float ss = 0.f;
  uint* dst = (uint*)qkdw + ((long)(b * CQK + c) * HWSZ >> 1) + (y0 + row) * 128 + xp0;
#pragma unroll
  for (int ch = 0; ch < 4; ++ch) {
    float o0[4] = {0.f, 0.f, 0.f, 0.f}, o1[4] = {0.f, 0.f, 0.f, 0.f};
#pragma unroll
    for (int dy = 0; dy < 3; ++dy) {
      const uint* L = &row_lds[(row + dy) * 132 + xp0 + ch * 4];
      uint4 q4 = *(const uint4*)L;
      uint2 q2 = *(const uint2*)(L + 4);
      uint u[6] = {q4.x, q4.y, q4.z, q4.w, q2.x, q2.y};
      float wa = w9[dy * 3 + 0], wb_ = w9[dy * 3 + 1], wc = w9[dy * 3 + 2];
#pragma unroll
      for (int j = 0; j < 4; ++j) {
        float f0 = bfhi(u[j]), f1 = bflo(u[j + 1]), f2 = bfhi(u[j + 1]), f3 = bflo(u[j + 2]);
        o0[j] += wa * f0 + wb_ * f1 + wc * f2;
        o1[j] += wa * f1 + wb_ * f2 + wc * f3;
      }
    }
    uint4 pk;
    pk.x = (uint)f2bf(o0[0]) | ((uint)f2bf(o1[0]) << 16);
    pk.y = (uint)f2bf(o0[1]) | ((uint)f2bf(o1[1]) << 16);
    pk.z = (uint)f2bf(o0[2]) | ((uint)f2bf(o1[2]) << 16);
    pk.w = (uint)f2bf(o0[3]) | ((uint)f2bf(o1[3]) << 16);
#pragma unroll
    for (int j = 0; j < 4; ++j) ss += o0[j] * o0[j] + o1[j] * o1[j];
    *(uint4*)(dst + ch * 4) = pk;
  }
#pragma unroll
  for (int off = 32; off; off >>= 1) ss += __shfl_down(ss, off);
  if ((tid & 63) == 0) red[tid >> 6] = ss;
  __syncthreads();
  if (tid == 0) sqp[(long)(b * CQK + c) * 8 + yt] = red[0] + red[1] + red[2] + red[3];
}

// ---------------- K2b v3: depthwise 3x3 on v channels, NATURAL [c][n] output --------
__global__ __launch_bounds__(256) void k2_vc(const ushort* __restrict__ qkv,
                                             ushort* __restrict__ vdw,
                                             const float* __restrict__ dww) {
  __shared__ uint row_lds[34 * 132];  // 17952 B
  int id = blockIdx.x;
  int yt = id & 7;
  int bc = id >> 3;
  int c = bc % 192;
  int b = bc / 192;
  int y0 = yt * 32;
  int tid = threadIdx.x;
  const uint* src = (const uint*)qkv + ((long)(b * C3 + CQK + c) * HWSZ >> 1);
  for (int i = tid; i < 4488; i += 256) {
    int r = i / 132, wx = i % 132;
    int gy = y0 - 1 + r;
    uint v = 0;
    if (gy >= 0 && gy < 256 && wx >= 1 && wx <= 128) v = src[gy * 128 + wx - 1];
    row_lds[i] = v;
  }
  float w9[9];
#pragma unroll
  for (int j = 0; j < 9; ++j) w9[j] = dww[(CQK + c) * 9 + j];
  __syncthreads();
  int row = tid >> 3;        // 0..31
  int xp0 = (tid & 7) * 16;  // u32 col base
  uint* dst = (uint*)vdw + ((long)(b * 192 + c) * HWSZ >> 1) + (y0 + row) * 128 + xp0;
#pragma unroll
  for (int ch = 0; ch < 4; ++ch) {
    float o0[4] = {0.f, 0.f, 0.f, 0.f}, o1[4] = {0.f, 0.f, 0.f, 0.f};
#pragma unroll
    for (int dy = 0; dy < 3; ++dy) {
      const uint* L = &row_lds[(row + dy) * 132 + xp0 + ch * 4];
      uint4 q4 = *(const uint4*)L;
      uint2 q2 = *(const uint2*)(L + 4);
      uint u[6] = {q4.x, q4.y, q4.z, q4.w, q2.x, q2.y};
      float wa = w9[dy * 3 + 0], wb_ = w9[dy * 3 + 1], wc = w9[dy * 3 + 2];
#pragma unroll
      for (int j = 0; j < 4; ++j) {
        float f0 = bfhi(u[j]), f1 = bflo(u[j + 1]), f2 = bfhi(u[j + 1]), f3 = bflo(u[j + 2]);
        o0[j] += wa * f0 + wb_ * f1 + wc * f2;
        o1[j] += wa * f1 + wb_ * f2 + wc * f3;
      }
    }
    uint4 pk;
    pk.x = (uint)f2bf(o0[0]) | ((uint)f2bf(o1[0]) << 16);
    pk.y = (uint)f2bf(o0[1]) | ((uint)f2bf(o1[1]) << 16);
    pk.z = (uint)f2bf(o0[2]) | ((uint)f2bf(o1[2]) << 16);
    pk.w = (uint)f2bf(o0[3]) | ((uint)f2bf(o1[3]) << 16);
    *(uint4*)(dst + ch * 4) = pk;
  }
}

// ---------------- K3a v2: attention logit partials (32 chunks, plain stores) --------
__global__ __launch_bounds__(256, 4) void k3_attn(const ushort* __restrict__ qkdw,
                                                  float* __restrict__ rawp) {
  __shared__ ushort qk_lds[96 * 136];  // rows padded to 272B
  int id = blockIdx.x;
  int chunk = id & 31;
  int bh = id >> 5;
  int b = bh >> 2, h = bh & 3;
  int tid = threadIdx.x;
  int lane = tid & 63, wv = tid >> 6;
  int lanelo = lane & 15, laneq = lane >> 4;
  f32x4 acc[3][3] = {};
  long kbase0 = (long)chunk * 2048;
  for (int it = 0; it < 16; ++it) {
    long kb = kbase0 + it * 128;
#pragma unroll
    for (int i = 0; i < 7; ++i) {
      int wbase = i * 256 + wv * 64;
      if (wbase < 1632) {
        int cc = wbase + lane;
        if (cc < 1632) {
          int row = cc / 17, sub = cc % 17;
          if (sub < 16) {
            int chn = (row < 48) ? (h * 48 + row) : (192 + h * 48 + row - 48);
            const ushort* g = qkdw + (long)(b * CQK + chn) * HWSZ + kb + sub * 8;
            async16((char*)qk_lds + wbase * 16, g);
          }
        }
      }
    }
    __syncthreads();
    bf16x8 af[3], bf[3];
#pragma unroll
    for (int mt = 0; mt < 3; ++mt)
      af[mt] = *(const bf16x8*)((const char*)qk_lds + (mt * 16 + lanelo) * 272 + wv * 64 + laneq * 16);
#pragma unroll
    for (int et = 0; et < 3; ++et)
      bf[et] = *(const bf16x8*)((const char*)qk_lds + (48 + et * 16 + lanelo) * 272 + wv * 64 + laneq * 16);
#pragma unroll
    for (int mt = 0; mt < 3; ++mt)
#pragma unroll
      for (int et = 0; et < 3; ++et)
        acc[mt][et] = __builtin_amdgcn_mfma_f32_16x16x32_bf16(af[mt], bf[et], acc[mt][et], 0, 0, 0);
    __syncthreads();
  }
  float* rb = rawp + ((long)bh * 32 + chunk) * 2304;
#pragma unroll
  for (int mt = 0; mt < 3; ++mt)
#pragma unroll
    for (int et = 0; et < 3; ++et)
#pragma unroll
      for (int r = 0; r < 4; ++r) {
        int d = mt * 16 + laneq * 4 + r;
        int e = et * 16 + lanelo;
        rb[d * 48 + e] = acc[mt][et][r];
      }
}

// ---------------- K3b v2: reduce partials + normalize + softmax + fold proj_w -------
__global__ __launch_bounds__(256) void k3_soft(const float* __restrict__ rawp,
                                               const float* __restrict__ sqp,
                                               const float* __restrict__ temp,
                                               const float* __restrict__ projw,
                                               ushort* __restrict__ M) {
  __shared__ float attn[48 * 48];
  __shared__ float iq[48], ik[48];
  int bh = blockIdx.x;
  int b = bh >> 2, h = bh & 3;
  int tid = threadIdx.x;
  if (tid < 48) {
    const float* p = sqp + (long)(b * CQK + h * 48 + tid) * 8;
    float s = 0.f;
#pragma unroll
    for (int k = 0; k < 8; ++k) s += p[k];
    iq[tid] = 1.f / fmaxf(sqrtf(s), 1e-12f);
  } else if (tid < 96) {
    int e = tid - 48;
    const float* p = sqp + (long)(b * CQK + 192 + h * 48 + e) * 8;
    float s = 0.f;
#pragma unroll
    for (int k = 0; k < 8; ++k) s += p[k];
    ik[e] = 1.f / fmaxf(sqrtf(s), 1e-12f);
  }
  __syncthreads();
  float t = temp[h];
  for (int i = tid; i < 2304; i += 256) {
    float s = 0.f;
    const float* rp = rawp + (long)bh * 32 * 2304 + i;
#pragma unroll 8
    for (int ch = 0; ch < 32; ++ch) s += rp[ch * 2304];
    int d = i / 48, e = i % 48;
    attn[i] = s * iq[d] * ik[e] * t;
  }
  __syncthreads();
  if (tid < 48) {
    float mx = -1e30f;
    for (int e = 0; e < 48; ++e) mx = fmaxf(mx, attn[tid * 48 + e]);
    float s = 0.f;
    for (int e = 0; e < 48; ++e) {
      float v = expf(attn[tid * 48 + e] - mx);
      attn[tid * 48 + e] = v;
      s += v;
    }
    float inv = 1.f / s;
    for (int e = 0; e < 48; ++e) attn[tid * 48 + e] *= inv;
  }
  __syncthreads();
  ushort* Mb = M + (long)b * 192 * 192;
  for (int i = tid; i < 192 * 48; i += 256) {
    int cp = i / 48, e = i % 48;
    const float* pw = projw + (long)cp * 192 + h * 48;
    float s = 0.f;
#pragma unroll 4
    for (int d = 0; d < 48; ++d) s += pw[d] * attn[d * 48 + e];
    Mb[(long)cp * 192 + h * 48 + e] = f2bf(s);
  }
}

extern "C" void kernel_launch(void* const* d_in, const int* in_sizes, int n_in,
                              void* d_out, int out_size, void* d_ws, size_t ws_size,
                              hipStream_t stream) {
  const float* x = (const float*)d_in[0];
  const float* qkv_w = (const float*)d_in[1];
  const float* dw_w = (const float*)d_in[2];
  const float* temp = (const float*)d_in[3];
  const float* proj_w = (const float*)d_in[4];

  char* ws = (char*)d_ws;
  ushort* xT = (ushort*)(ws);                      // 100,663,296 B ; reused as vdw [c][n]
  ushort* QKV = (ushort*)(ws + 100663296L);        // 301,989,888 B
  ushort* qkdw = (ushort*)(ws + 402653184L);       // 201,326,592 B
  ushort* wbf = (ushort*)(ws + 603979776L);        // 221,184 B
  ushort* Mbf = (ushort*)(ws + 604200960L);        // 294,912 B
  float* sqp = (float*)(ws + 604495872L);          // 49,152 B
  float* rawp = (float*)(ws + 604545024L);         // 4,718,592 B

  k0_transpose<<<4096, 256, 0, stream>>>(x, xT);
  k0_cvtw<<<108, 256, 0, stream>>>(qkv_w, wbf, 110592);
  gemm_nt<ushort><<<6144, 512, 0, stream>>>(wbf, 0L, xT, (long)HWSZ * CIN, QKV, (long)C3 * HWSZ, 3);
  k2_qk<<<12288, 256, 0, stream>>>(QKV, qkdw, sqp, dw_w);
  k2_vc<<<6144, 256, 0, stream>>>(QKV, xT, dw_w);  // vdw [c][n] overwrites xT (gemm done)
  k3_attn<<<512, 256, 0, stream>>>(qkdw, rawp);
  k3_soft<<<16, 256, 0, stream>>>(rawp, sqp, temp, proj_w, Mbf);
  gemm_nn<float><<<4096, 512, 0, stream>>>(Mbf, (long)192 * 192, xT, (long)192 * HWSZ,
                                           (float*)d_out, (long)CIN * HWSZ, 1);
}

// Round 6
// 833.249 us; speedup vs baseline: 1.2856x; 1.2486x over previous
//
#include <hip/hip_runtime.h>

typedef unsigned int uint;
typedef unsigned short ushort;
typedef __attribute__((ext_vector_type(8))) short bf16x8;
typedef __attribute__((ext_vector_type(4))) float f32x4;

#define HWSZ 65536
#define CIN 192
#define C3 576
#define CQK 384

typedef __attribute__((address_space(1))) const void gvoid_c;
typedef __attribute__((address_space(3))) void lvoid;

__device__ __forceinline__ void async16(void* l, const void* g) {
  __builtin_amdgcn_global_load_lds((gvoid_c*)g, (lvoid*)l, 16, 0, 0);
}

__device__ __forceinline__ ushort f2bf(float f) {
  uint u = __float_as_uint(f);
  return (ushort)((u + 0x7fffu + ((u >> 16) & 1u)) >> 16);
}
__device__ __forceinline__ float bflo(uint u) { return __uint_as_float(u << 16); }
__device__ __forceinline__ float bfhi(uint u) { return __uint_as_float(u & 0xffff0000u); }

// ---------------- K0b: fp32 -> bf16 flat convert (qkv_w) ----------------
__global__ __launch_bounds__(256) void k0_cvtw(const float* __restrict__ w,
                                               ushort* __restrict__ wb, int nelem) {
  int i = (blockIdx.x * 256 + threadIdx.x) * 4;
  if (i + 3 < nelem) {
    float4 f = *(const float4*)(w + i);
    ushort4 o;
    o.x = f2bf(f.x); o.y = f2bf(f.y); o.z = f2bf(f.z); o.w = f2bf(f.w);
    *(ushort4*)(wb + i) = o;
  }
}

// ---------------- GEMM NN: D[M,HW] = A[M,192] * B[192,HW] (B in [c][n]) ------------
// B-tile reg-staged coalesced from [c][n] (fp32 or bf16 source; fp32 converts on the
// fly — this fuses the old k0_transpose), written transposed into the [n][c] LDS
// layout the MFMA path consumes. XOR block-swizzle keeps ds_write_b16 2-way.
// BM=192, BN=64 (round-2 proven traffic: FETCH=B once, WRITE=D exactly).
// DO NOT widen BN to 128: rounds 3-4 measured 2.3x fetch+write amplification
// (suspect L2-set aliasing of 128KB-strided dirty lines), regardless of block order.
template <typename TIn, typename TOut>
__global__ __launch_bounds__(512, 6) void gemm_nn(const ushort* __restrict__ A, long a_bstride,
                                                  const TIn* __restrict__ B, long b_bstride,
                                                  TOut* __restrict__ D, long d_bstride,
                                                  int mtiles) {
  __shared__ ushort lds[18432];  // A: 27648B, B(transposed): 64*144B = 9216B
  int idx = blockIdx.x;
  int ntile = idx & 1023;        // ntile fastest: B passes time-separated, L3 dedupes
  int bm = idx >> 10;
  int mtile = bm % mtiles;
  int b = bm / mtiles;
  int tid = threadIdx.x;
  int lane = tid & 63;
  int wv = tid >> 6;
  int wm = wv >> 1, wn = wv & 1;
  int lanelo = lane & 15, laneq = lane >> 4;

  const ushort* Ab = A + a_bstride * b + (long)mtile * 192 * 192;
  const TIn* Bb = B + b_bstride * b + (long)ntile * 64;  // [c][n] layout, row stride HWSZ

  int cs = tid >> 3, chk = tid & 7;     // cs: 0..63 c-slice row, chk: n-octet
  ushort* lb = lds + 13824;             // B region, ushort units (27648 B)

  f32x4 acc[3][2] = {};

  for (int kit = 0; kit < 3; ++kit) {
    // B: coalesced reg load (8 elems/thread; 256B or 128B segments per c-row)
    const TIn* bsrc = Bb + (long)(kit * 64 + cs) * HWSZ + chk * 8;
    ushort u8[8];
    if constexpr (sizeof(TIn) == 4) {
      float4 f0 = *(const float4*)bsrc;
      float4 f1 = *(const float4*)(bsrc + 4);
      u8[0] = f2bf(f0.x); u8[1] = f2bf(f0.y); u8[2] = f2bf(f0.z); u8[3] = f2bf(f0.w);
      u8[4] = f2bf(f1.x); u8[5] = f2bf(f1.y); u8[6] = f2bf(f1.z); u8[7] = f2bf(f1.w);
    } else {
      union { uint4 q; ushort u[8]; } pk;
      pk.q = *(const uint4*)bsrc;
#pragma unroll
      for (int j = 0; j < 8; ++j) u8[j] = pk.u[j];
    }
    // A: async16 direct-to-LDS, 192 rows x 8 subs
#pragma unroll
    for (int i = 0; i < 4; ++i) {
      int wbase = i * 512 + wv * 64;
      if (wbase < 1728) {
        int cc = wbase + lane;
        int row = cc / 9, sub = cc % 9;
        if (sub < 8) {
          const ushort* g = Ab + row * 192 + kit * 64 + sub * 8;
          async16((char*)lds + wbase * 16, g);
        }
      }
    }
    // B: transposed write, col-block swizzled by (n>>3)&7 (== chk here)
    int colbase = (((cs >> 3) ^ chk) << 3) | (cs & 7);
#pragma unroll
    for (int j = 0; j < 8; ++j)
      lb[(chk * 8 + j) * 72 + colbase] = u8[j];
    __syncthreads();
#pragma unroll
    for (int ks = 0; ks < 2; ++ks) {
      bf16x8 af[3], bf[2];
#pragma unroll
      for (int mt = 0; mt < 3; ++mt) {
        int m = wm * 48 + mt * 16 + lanelo;
        af[mt] = *(const bf16x8*)((const char*)lds + m * 144 + ks * 64 + laneq * 16);
      }
#pragma unroll
      for (int nt = 0; nt < 2; ++nt) {
        int n = wn * 32 + nt * 16 + lanelo;
        int cb = ks * 4 + laneq;
        bf[nt] = *(const bf16x8*)((const char*)lds + 27648 + n * 144 +
                                  ((cb ^ ((n >> 3) & 7)) << 4));
      }
#pragma unroll
      for (int mt = 0; mt < 3; ++mt)
#pragma unroll
        for (int nt = 0; nt < 2; ++nt)
          acc[mt][nt] = __builtin_amdgcn_mfma_f32_16x16x32_bf16(af[mt], bf[nt], acc[mt][nt], 0, 0, 0);
    }
    __syncthreads();
  }

  TOut* Db = D + d_bstride * b;
  int colb = ntile * 64 + wn * 32 + lanelo;
#pragma unroll
  for (int mt = 0; mt < 3; ++mt)
#pragma unroll
    for (int nt = 0; nt < 2; ++nt)
#pragma unroll
      for (int r = 0; r < 4; ++r) {
        long row = (long)(mtile * 192 + wm * 48 + mt * 16 + laneq * 4 + r);
        float v = acc[mt][nt][r];
        if constexpr (sizeof(TOut) == 2)
          Db[row * HWSZ + colb + nt * 16] = f2bf(v);
        else
          Db[row * HWSZ + colb + nt * 16] = v;
      }
}

// ---------------- K2a v2: depthwise 3x3 on q,k channels + sq-norm partials ----------
__global__ __launch_bounds__(256) void k2_qk(const ushort* __restrict__ qkv,
                                             ushort* __restrict__ qkdw,
                                             float* __restrict__ sqp,
                                             const float* __restrict__ dww) {
  __shared__ uint row_lds[34 * 132];  // 17952 B
  __shared__ float red[4];
  int id = blockIdx.x;
  int yt = id & 7;
  int bc = id >> 3;
  int c = bc % CQK;
  int b = bc / CQK;
  int y0 = yt * 32;
  int tid = threadIdx.x;
  const uint* src = (const uint*)qkv + ((long)(b * C3 + c) * HWSZ >> 1);
  for (int i = tid; i < 4488; i += 256) {
    int r = i / 132, wx = i % 132;
    int gy = y0 - 1 + r;
    uint v = 0;
    if (gy >= 0 && gy < 256 && wx >= 1 && wx <= 128) v = src[gy * 128 + wx - 1];
    row_lds[i] = v;
  }
  float w9[9];
#pragma unroll
  for (int j = 0; j < 9; ++j) w9[j] = dww[c * 9 + j];
  __syncthreads();
  int row = tid >> 3;        // 0..31
  int xp0 = (tid & 7) * 16;  // u32 col base
  float ss = 0.f;
  uint* dst = (uint*)qkdw + ((long)(b * CQK + c) * HWSZ >> 1) + (y0 + row) * 128 + xp0;
#pragma unroll
  for (int ch = 0; ch < 4; ++ch) {
    float o0[4] = {0.f, 0.f, 0.f, 0.f}, o1[4] = {0.f, 0.f, 0.f, 0.f};
#pragma unroll
    for (int dy = 0; dy < 3; ++dy) {
      const uint* L = &row_lds[(row + dy) * 132 + xp0 + ch * 4];
      uint4 q4 = *(const uint4*)L;
      uint2 q2 = *(const uint2*)(L + 4);
      uint u[6] = {q4.x, q4.y, q4.z, q4.w, q2.x, q2.y};
      float wa = w9[dy * 3 + 0], wb_ = w9[dy * 3 + 1], wc = w9[dy * 3 + 2];
#pragma unroll
      for (int j = 0; j < 4; ++j) {
        float f0 = bfhi(u[j]), f1 = bflo(u[j + 1]), f2 = bfhi(u[j + 1]), f3 = bflo(u[j + 2]);
        o0[j] += wa * f0 + wb_ * f1 + wc * f2;
        o1[j] += wa * f1 + wb_ * f2 + wc * f3;
      }
    }
    uint4 pk;
    pk.x = (uint)f2bf(o0[0]) | ((uint)f2bf(o1[0]) << 16);
    pk.y = (uint)f2bf(o0[1]) | ((uint)f2bf(o1[1]) << 16);
    pk.z = (uint)f2bf(o0[2]) | ((uint)f2bf(o1[2]) << 16);
    pk.w = (uint)f2bf(o0[3]) | ((uint)f2bf(o1[3]) << 16);
#pragma unroll
    for (int j = 0; j < 4; ++j) ss += o0[j] * o0[j] + o1[j] * o1[j];
    *(uint4*)(dst + ch * 4) = pk;
  }
#pragma unroll
  for (int off = 32; off; off >>= 1) ss += __shfl_down(ss, off);
  if ((tid & 63) == 0) red[tid >> 6] = ss;
  __syncthreads();
  if (tid == 0) sqp[(long)(b * CQK + c) * 8 + yt] = red[0] + red[1] + red[2] + red[3];
}

// ---------------- K2b v3: depthwise 3x3 on v channels, NATURAL [c][n] output --------
__global__ __launch_bounds__(256) void k2_vc(const ushort* __restrict__ qkv,
                                             ushort* __restrict__ vdw,
                                             const float* __restrict__ dww) {
  __shared__ uint row_lds[34 * 132];  // 17952 B
  int id = blockIdx.x;
  int yt = id & 7;
  int bc = id >> 3;
  int c = bc % 192;
  int b = bc / 192;
  int y0 = yt * 32;
  int tid = threadIdx.x;
  const uint* src = (const uint*)qkv + ((long)(b * C3 + CQK + c) * HWSZ >> 1);
  for (int i = tid; i < 4488; i += 256) {
    int r = i / 132, wx = i % 132;
    int gy = y0 - 1 + r;
    uint v = 0;
    if (gy >= 0 && gy < 256 && wx >= 1 && wx <= 128) v = src[gy * 128 + wx - 1];
    row_lds[i] = v;
  }
  float w9[9];
#pragma unroll
  for (int j = 0; j < 9; ++j) w9[j] = dww[(CQK + c) * 9 + j];
  __syncthreads();
  int row = tid >> 3;        // 0..31
  int xp0 = (tid & 7) * 16;  // u32 col base
  uint* dst = (uint*)vdw + ((long)(b * 192 + c) * HWSZ >> 1) + (y0 + row) * 128 + xp0;
#pragma unroll
  for (int ch = 0; ch < 4; ++ch) {
    float o0[4] = {0.f, 0.f, 0.f, 0.f}, o1[4] = {0.f, 0.f, 0.f, 0.f};
#pragma unroll
    for (int dy = 0; dy < 3; ++dy) {
      const uint* L = &row_lds[(row + dy) * 132 + xp0 + ch * 4];
      uint4 q4 = *(const uint4*)L;
      uint2 q2 = *(const uint2*)(L + 4);
      uint u[6] = {q4.x, q4.y, q4.z, q4.w, q2.x, q2.y};
      float wa = w9[dy * 3 + 0], wb_ = w9[dy * 3 + 1], wc = w9[dy * 3 + 2];
#pragma unroll
      for (int j = 0; j < 4; ++j) {
        float f0 = bfhi(u[j]), f1 = bflo(u[j + 1]), f2 = bfhi(u[j + 1]), f3 = bflo(u[j + 2]);
        o0[j] += wa * f0 + wb_ * f1 + wc * f2;
        o1[j] += wa * f1 + wb_ * f2 + wc * f3;
      }
    }
    uint4 pk;
    pk.x = (uint)f2bf(o0[0]) | ((uint)f2bf(o1[0]) << 16);
    pk.y = (uint)f2bf(o0[1]) | ((uint)f2bf(o1[1]) << 16);
    pk.z = (uint)f2bf(o0[2]) | ((uint)f2bf(o1[2]) << 16);
    pk.w = (uint)f2bf(o0[3]) | ((uint)f2bf(o1[3]) << 16);
    *(uint4*)(dst + ch * 4) = pk;
  }
}

// ---------------- K3a v2: attention logit partials (32 chunks, plain stores) --------
__global__ __launch_bounds__(256, 4) void k3_attn(const ushort* __restrict__ qkdw,
                                                  float* __restrict__ rawp) {
  __shared__ ushort qk_lds[96 * 136];  // rows padded to 272B
  int id = blockIdx.x;
  int chunk = id & 31;
  int bh = id >> 5;
  int b = bh >> 2, h = bh & 3;
  int tid = threadIdx.x;
  int lane = tid & 63, wv = tid >> 6;
  int lanelo = lane & 15, laneq = lane >> 4;
  f32x4 acc[3][3] = {};
  long kbase0 = (long)chunk * 2048;
  for (int it = 0; it < 16; ++it) {
    long kb = kbase0 + it * 128;
#pragma unroll
    for (int i = 0; i < 7; ++i) {
      int wbase = i * 256 + wv * 64;
      if (wbase < 1632) {
        int cc = wbase + lane;
        if (cc < 1632) {
          int row = cc / 17, sub = cc % 17;
          if (sub < 16) {
            int chn = (row < 48) ? (h * 48 + row) : (192 + h * 48 + row - 48);
            const ushort* g = qkdw + (long)(b * CQK + chn) * HWSZ + kb + sub * 8;
            async16((char*)qk_lds + wbase * 16, g);
          }
        }
      }
    }
    __syncthreads();
    bf16x8 af[3], bf[3];
#pragma unroll
    for (int mt = 0; mt < 3; ++mt)
      af[mt] = *(const bf16x8*)((const char*)qk_lds + (mt * 16 + lanelo) * 272 + wv * 64 + laneq * 16);
#pragma unroll
    for (int et = 0; et < 3; ++et)
      bf[et] = *(const bf16x8*)((const char*)qk_lds + (48 + et * 16 + lanelo) * 272 + wv * 64 + laneq * 16);
#pragma unroll
    for (int mt = 0; mt < 3; ++mt)
#pragma unroll
      for (int et = 0; et < 3; ++et)
        acc[mt][et] = __builtin_amdgcn_mfma_f32_16x16x32_bf16(af[mt], bf[et], acc[mt][et], 0, 0, 0);
    __syncthreads();
  }
  float* rb = rawp + ((long)bh * 32 + chunk) * 2304;
#pragma unroll
  for (int mt = 0; mt < 3; ++mt)
#pragma unroll
    for (int et = 0; et < 3; ++et)
#pragma unroll
      for (int r = 0; r < 4; ++r) {
        int d = mt * 16 + laneq * 4 + r;
        int e = et * 16 + lanelo;
        rb[d * 48 + e] = acc[mt][et][r];
      }
}

// ---------------- K3b v2: reduce partials + normalize + softmax + fold proj_w -------
__global__ __launch_bounds__(256) void k3_soft(const float* __restrict__ rawp,
                                               const float* __restrict__ sqp,
                                               const float* __restrict__ temp,
                                               const float* __restrict__ projw,
                                               ushort* __restrict__ M) {
  __shared__ float attn[48 * 48];
  __shared__ float iq[48], ik[48];
  int bh = blockIdx.x;
  int b = bh >> 2, h = bh & 3;
  int tid = threadIdx.x;
  if (tid < 48) {
    const float* p = sqp + (long)(b * CQK + h * 48 + tid) * 8;
    float s = 0.f;
#pragma unroll
    for (int k = 0; k < 8; ++k) s += p[k];
    iq[tid] = 1.f / fmaxf(sqrtf(s), 1e-12f);
  } else if (tid < 96) {
    int e = tid - 48;
    const float* p = sqp + (long)(b * CQK + 192 + h * 48 + e) * 8;
    float s = 0.f;
#pragma unroll
    for (int k = 0; k < 8; ++k) s += p[k];
    ik[e] = 1.f / fmaxf(sqrtf(s), 1e-12f);
  }
  __syncthreads();
  float t = temp[h];
  for (int i = tid; i < 2304; i += 256) {
    float s = 0.f;
    const float* rp = rawp + (long)bh * 32 * 2304 + i;
#pragma unroll 8
    for (int ch = 0; ch < 32; ++ch) s += rp[ch * 2304];
    int d = i / 48, e = i % 48;
    attn[i] = s * iq[d] * ik[e] * t;
  }
  __syncthreads();
  if (tid < 48) {
    float mx = -1e30f;
    for (int e = 0; e < 48; ++e) mx = fmaxf(mx, attn[tid * 48 + e]);
    float s = 0.f;
    for (int e = 0; e < 48; ++e) {
      float v = expf(attn[tid * 48 + e] - mx);
      attn[tid * 48 + e] = v;
      s += v;
    }
    float inv = 1.f / s;
    for (int e = 0; e < 48; ++e) attn[tid * 48 + e] *= inv;
  }
  __syncthreads();
  ushort* Mb = M + (long)b * 192 * 192;
  for (int i = tid; i < 192 * 48; i += 256) {
    int cp = i / 48, e = i % 48;
    const float* pw = projw + (long)cp * 192 + h * 48;
    float s = 0.f;
#pragma unroll 4
    for (int d = 0; d < 48; ++d) s += pw[d] * attn[d * 48 + e];
    Mb[(long)cp * 192 + h * 48 + e] = f2bf(s);
  }
}

extern "C" void kernel_launch(void* const* d_in, const int* in_sizes, int n_in,
                              void* d_out, int out_size, void* d_ws, size_t ws_size,
                              hipStream_t stream) {
  const float* x = (const float*)d_in[0];
  const float* qkv_w = (const float*)d_in[1];
  const float* dw_w = (const float*)d_in[2];
  const float* temp = (const float*)d_in[3];
  const float* proj_w = (const float*)d_in[4];

  char* ws = (char*)d_ws;
  ushort* vdw = (ushort*)(ws);                     // 100,663,296 B  [c][n] v-conv out
  ushort* QKV = (ushort*)(ws + 100663296L);        // 301,989,888 B
  ushort* qkdw = (ushort*)(ws + 402653184L);       // 201,326,592 B
  ushort* wbf = (ushort*)(ws + 603979776L);        // 221,184 B
  ushort* Mbf = (ushort*)(ws + 604200960L);        // 294,912 B
  float* sqp = (float*)(ws + 604495872L);          // 49,152 B
  float* rawp = (float*)(ws + 604545024L);         // 4,718,592 B

  k0_cvtw<<<108, 256, 0, stream>>>(qkv_w, wbf, 110592);
  // fused QKV: reads x fp32 [c][n] directly (k0_transpose eliminated)
  gemm_nn<float, ushort><<<12288, 512, 0, stream>>>(wbf, 0L, x, (long)CIN * HWSZ,
                                                    QKV, (long)C3 * HWSZ, 3);
  k2_qk<<<12288, 256, 0, stream>>>(QKV, qkdw, sqp, dw_w);
  k2_vc<<<6144, 256, 0, stream>>>(QKV, vdw, dw_w);
  k3_attn<<<512, 256, 0, stream>>>(qkdw, rawp);
  k3_soft<<<16, 256, 0, stream>>>(rawp, sqp, temp, proj_w, Mbf);
  gemm_nn<ushort, float><<<4096, 512, 0, stream>>>(Mbf, (long)192 * 192, vdw, (long)192 * HWSZ,
                                                   (float*)d_out, (long)CIN * HWSZ, 1);
}